// Round 6
// baseline (189.847 us; speedup 1.0000x reference)
//
#include <hip/hip_runtime.h>
#include <stdint.h>

#define NHEADS 12
#define HDIM   64
#define NB     4
#define SQ     1024
#define DM     768
#define NROWS  (NB*SQ)      // 4096
#define NWE    (DM*DM)      // 589824
#define NXE    (NROWS*DM)   // 3145728

typedef __attribute__((ext_vector_type(8))) short short8;
typedef __attribute__((ext_vector_type(4))) float f32x4;

__device__ __forceinline__ unsigned short f2bf(float f) {
  union { float f; unsigned u; } v; v.f = f;
  return (unsigned short)((v.u + 0x7fffu + ((v.u >> 16) & 1u)) >> 16);
}

// pack two fp32 -> two bf16 in a dword (lo = first arg), pure verified ALU
__device__ __forceinline__ unsigned pack2bf(float lo, float hi) {
  return (unsigned)f2bf(lo) | ((unsigned)f2bf(hi) << 16);
}

__device__ __forceinline__ void gload16(const void* g, void* l) {
  __builtin_amdgcn_global_load_lds((__attribute__((address_space(1))) void*)(void*)g,
                                   (__attribute__((address_space(3))) void*)l, 16, 0, 0);
}

// ---------------- prep: fp32 -> bf16 conversions + box centers ----------------
__global__ __launch_bounds__(256) void prep_kernel(
    const float* __restrict__ x, const float* __restrict__ Wq, const float* __restrict__ Wk,
    const float* __restrict__ Wv, const float* __restrict__ Wo, const float* __restrict__ boxes,
    unsigned short* __restrict__ xb, unsigned short* __restrict__ wcat,
    unsigned short* __restrict__ wob, float2* __restrict__ centers) {
  int i = blockIdx.x * 256 + threadIdx.x;
  if (i < NXE) { xb[i] = f2bf(x[i]); return; }
  i -= NXE;
  if (i < NWE) {
    wcat[i]           = f2bf(Wq[i]);
    wcat[NWE + i]     = f2bf(Wk[i]);
    wcat[2 * NWE + i] = f2bf(Wv[i]);
    wob[i]            = f2bf(Wo[i]);
    return;
  }
  i -= NWE;
  if (i < NROWS) {
    float4 bx = ((const float4*)boxes)[i];
    centers[i] = make_float2((bx.x + bx.z) * 0.5f, (bx.y + bx.w) * 0.5f);
  }
}

// ---------------- NT GEMM: C[M,N] = A[M,K] * B[N,K]^T  (bf16 in, fp32 acc) ----
// 128x128 tile, 4 waves (2x2 of 64x64), 16x16x32 bf16 MFMA, global_load_lds.
// EPI=0: QKV epilogue (Q scaled by 0.125*log2e for exp2-domain softmax)
// EPI=1: fp32 out = acc + b0[n]
template <int EPI>
__global__ __launch_bounds__(256, 2) void gemm_bt(
    const unsigned short* __restrict__ A, const unsigned short* __restrict__ Bw,
    int K, int tiles_n,
    const float* __restrict__ b0, const float* __restrict__ b1, const float* __restrict__ b2,
    unsigned short* __restrict__ outQ, unsigned short* __restrict__ outK,
    unsigned short* __restrict__ outVt, float* __restrict__ outF) {
  __shared__ unsigned short lA[128 * 32];
  __shared__ unsigned short lB[128 * 32];
  const int tid = threadIdx.x, wave = tid >> 6, lane = tid & 63;
  const int tm = blockIdx.x / tiles_n, tn = blockIdx.x % tiles_n;
  const int wr = wave >> 1, wc = wave & 1;
  const int g = lane >> 4, c16 = lane & 15, kb8 = g * 8;

  f32x4 acc[4][4];
#pragma unroll
  for (int m = 0; m < 4; m++)
#pragma unroll
    for (int n = 0; n < 4; n++) acc[m][n] = (f32x4){0.f, 0.f, 0.f, 0.f};

  const unsigned short* Abase = A + (size_t)tm * 128 * K;
  const unsigned short* Bbase = Bw + (size_t)tn * 128 * K;
  const int lin0 = wave * 1024 + lane * 16;
  const int row0 = lin0 >> 6, cb0 = lin0 & 63;
  const int lin1 = lin0 + 4096;
  const int row1 = lin1 >> 6, cb1 = lin1 & 63;

  for (int kt = 0; kt < K; kt += 32) {
    __syncthreads();
    gload16((const char*)(Abase + (size_t)row0 * K + kt) + cb0, (char*)lA + wave * 1024);
    gload16((const char*)(Abase + (size_t)row1 * K + kt) + cb1, (char*)lA + wave * 1024 + 4096);
    gload16((const char*)(Bbase + (size_t)row0 * K + kt) + cb0, (char*)lB + wave * 1024);
    gload16((const char*)(Bbase + (size_t)row1 * K + kt) + cb1, (char*)lB + wave * 1024 + 4096);
    __syncthreads();
    short8 a[4], b[4];
#pragma unroll
    for (int m = 0; m < 4; m++) a[m] = *(const short8*)&lA[(wr * 64 + m * 16 + c16) * 32 + kb8];
#pragma unroll
    for (int n = 0; n < 4; n++) b[n] = *(const short8*)&lB[(wc * 64 + n * 16 + c16) * 32 + kb8];
#pragma unroll
    for (int m = 0; m < 4; m++)
#pragma unroll
      for (int n = 0; n < 4; n++)
        acc[m][n] = __builtin_amdgcn_mfma_f32_16x16x32_bf16(a[m], b[n], acc[m][n], 0, 0, 0);
  }

  // C/D layout (m89): col = lane&15, row = (lane>>4)*4 + r
#pragma unroll
  for (int m = 0; m < 4; m++) {
    const int gm0 = tm * 128 + wr * 64 + m * 16 + g * 4;
    const int bb = gm0 >> 10, ss0 = gm0 & 1023;
#pragma unroll
    for (int n = 0; n < 4; n++) {
      const int gn = tn * 128 + wc * 64 + n * 16 + c16;
      if (EPI == 0) {
        const int which = gn / DM, nn = gn - which * DM;
        const int h = nn >> 6, dh = nn & 63;
        const float bias = (which == 0 ? b0 : which == 1 ? b1 : b2)[nn];
        // fold 1/sqrt(Dh) * log2(e) into Q (exp2-domain softmax)
        const float scale = (which == 0) ? 0.1803368801f : 1.0f;
        if (which == 2) {
          ushort4 pk;
          pk.x = f2bf(acc[m][n][0] + bias);
          pk.y = f2bf(acc[m][n][1] + bias);
          pk.z = f2bf(acc[m][n][2] + bias);
          pk.w = f2bf(acc[m][n][3] + bias);
          *(ushort4*)&outVt[(((size_t)bb * NHEADS + h) * HDIM + dh) * SQ + ss0] = pk;
        } else {
          unsigned short* dst = (which == 0 ? outQ : outK) + ((size_t)bb * NHEADS + h) * SQ * HDIM;
#pragma unroll
          for (int r = 0; r < 4; r++)
            dst[(size_t)(ss0 + r) * HDIM + dh] = f2bf((acc[m][n][r] + bias) * scale);
        }
      } else {
        const float bias = b0[gn];
#pragma unroll
        for (int r = 0; r < 4; r++)
          outF[(size_t)(gm0 + r) * DM + gn] = acc[m][n][r] + bias;
      }
    }
  }
}

// ---------------- fused spatial attention v5 (split-KV, 2x occupancy) --------
// Block = 32 q-rows; wave = 16 q-rows x 512 tokens (wave&1 = q-half,
// wave>>1 = token-half). Partials merged through LDS (flash combine).
// grid: 1536 blocks = 48 bh * 32 qtiles -> 6 blocks/CU, 6 waves/SIMD.
#define KVB  128
#define PSTR 136  // LDS P row stride in shorts (128 + 8 pad)
__global__ __launch_bounds__(256, 6) void attn_kernel(
    const unsigned short* __restrict__ Qb, const unsigned short* __restrict__ Kb,
    const unsigned short* __restrict__ Vt, const float2* __restrict__ centers,
    const float* __restrict__ sbias, unsigned short* __restrict__ attb) {
  __shared__ float2 cent_s[SQ];                 // 8192 B
  __shared__ unsigned short plds[4][16 * PSTR]; // 17408 B (reused for combine)
  const int tid = threadIdx.x, wave = tid >> 6, lane = tid & 63;
  const int g = lane >> 4, c16 = lane & 15, kb8 = g * 8;
  const int bid = blockIdx.x;
  const int xcd = bid & 7, li = bid >> 3;       // li in 0..191
  const int bh = xcd * 6 + (li >> 5);
  const int qt = li & 31;                       // 32-row q tile
  const int b = bh / NHEADS, h = bh - b * NHEADS;
  const float sb = sbias[h] * 1.44269504f;      // exp2-domain bias coefficient

  const unsigned short* Qh = Qb + (size_t)bh * SQ * HDIM;
  const unsigned short* Kh = Kb + (size_t)bh * SQ * HDIM;
  const unsigned short* Vh = Vt + (size_t)bh * HDIM * SQ;

  for (int i = tid; i < SQ; i += 256) cent_s[i] = centers[b * SQ + i];
  __syncthreads();

  const int qhalf = wave & 1, khalf = wave >> 1;
  const int q = qt * 32 + qhalf * 16 + c16;     // this lane's q-row
  short8 qf[2];
  qf[0] = *(const short8*)&Qh[(size_t)q * HDIM + kb8];
  qf[1] = *(const short8*)&Qh[(size_t)q * HDIM + 32 + kb8];
  const float2 cq = cent_s[q];

  float mreg = -1e30f, lreg = 0.f;              // lreg: per-lane partial sum
  f32x4 oacc[4];
#pragma unroll
  for (int dd = 0; dd < 4; dd++) oacc[dd] = (f32x4){0.f, 0.f, 0.f, 0.f};

  const int tb0 = khalf * (SQ / 2);
#pragma unroll 1
  for (int tb = tb0; tb < tb0 + SQ / 2; tb += KVB) {
    // --- 1. QK^T swapped: lane holds 32 token-scores for its q-row ---
    f32x4 sv[8];
#pragma unroll
    for (int cc = 0; cc < 8; cc++) {
      short8 k0 = *(const short8*)&Kh[(size_t)(tb + cc * 16 + c16) * HDIM + kb8];
      short8 k1 = *(const short8*)&Kh[(size_t)(tb + cc * 16 + c16) * HDIM + 32 + kb8];
      f32x4 s = (f32x4){0.f, 0.f, 0.f, 0.f};
      s = __builtin_amdgcn_mfma_f32_16x16x32_bf16(k0, qf[0], s, 0, 0, 0);
      s = __builtin_amdgcn_mfma_f32_16x16x32_bf16(k1, qf[1], s, 0, 0, 0);
      sv[cc] = s;
    }
    // --- 2. spatial bias (vectorized cent_s reads, raw v_sqrt) ---
#pragma unroll
    for (int cc = 0; cc < 8; cc++) {
      const float4* cp = (const float4*)&cent_s[tb + cc * 16 + g * 4];
      float4 c01 = cp[0], c23 = cp[1];
      float dx, dy;
      dx = cq.x - c01.x; dy = cq.y - c01.y;
      sv[cc][0] -= __builtin_amdgcn_sqrtf(dx * dx + dy * dy) * sb;
      dx = cq.x - c01.z; dy = cq.y - c01.w;
      sv[cc][1] -= __builtin_amdgcn_sqrtf(dx * dx + dy * dy) * sb;
      dx = cq.x - c23.x; dy = cq.y - c23.y;
      sv[cc][2] -= __builtin_amdgcn_sqrtf(dx * dx + dy * dy) * sb;
      dx = cq.x - c23.z; dy = cq.y - c23.w;
      sv[cc][3] -= __builtin_amdgcn_sqrtf(dx * dx + dy * dy) * sb;
    }
    // --- 3. defer-max online softmax (no shfl in common path) ---
    float lm = -1e30f;
#pragma unroll
    for (int cc = 0; cc < 8; cc++) {
      float a0 = fmaxf(sv[cc][0], sv[cc][1]), a1 = fmaxf(sv[cc][2], sv[cc][3]);
      lm = fmaxf(lm, fmaxf(a0, a1));
    }
    if (!__all(lm <= mreg + 8.0f)) {
      float vmax = fmaxf(lm, __shfl_xor(lm, 16));
      vmax = fmaxf(vmax, __shfl_xor(vmax, 32));
      const float mn = fmaxf(mreg, vmax);
      const float sc = __builtin_amdgcn_exp2f(mreg - mn);
      lreg *= sc;
#pragma unroll
      for (int dd = 0; dd < 4; dd++)
#pragma unroll
        for (int r = 0; r < 4; r++) oacc[dd][r] *= sc;
      mreg = mn;
    }
    float ps = 0.f;
#pragma unroll
    for (int cc = 0; cc < 8; cc++)
#pragma unroll
      for (int r = 0; r < 4; r++) {
        sv[cc][r] = __builtin_amdgcn_exp2f(sv[cc][r] - mreg);
        ps += sv[cc][r];
      }
    lreg += ps;
    // --- 4. P -> per-wave LDS [q-row][token] ---
#pragma unroll
    for (int cc = 0; cc < 8; cc++) {
      uint2 u;
      u.x = pack2bf(sv[cc][0], sv[cc][1]);
      u.y = pack2bf(sv[cc][2], sv[cc][3]);
      *(uint2*)&plds[wave][c16 * PSTR + cc * 16 + g * 4] = u;
    }
    // --- 5. PV: O^T[d,q] = mfma(V-rows, P-rows) ---
#pragma unroll
    for (int kc = 0; kc < 4; kc++) {
      short8 pf = *(const short8*)&plds[wave][c16 * PSTR + kc * 32 + kb8];
#pragma unroll
      for (int dd = 0; dd < 4; dd++) {
        short8 vf = *(const short8*)&Vh[(size_t)(dd * 16 + c16) * SQ + tb + kc * 32 + kb8];
        oacc[dd] = __builtin_amdgcn_mfma_f32_16x16x32_bf16(vf, pf, oacc[dd], 0, 0, 0);
      }
    }
  }

  // --- combine the two token-halves (waves w and w+2 share 16 q-rows) ---
  __syncthreads();  // all P-reads of plds complete before reuse
  float* cb = (float*)&plds[0][0];  // 2 slots x 64 lanes x 20 floats = 10240 B
  if (wave >= 2) {
    float* myb = cb + (size_t)(wave - 2) * 1280 + lane * 20;
#pragma unroll
    for (int dd = 0; dd < 4; dd++) *(f32x4*)(myb + dd * 4) = oacc[dd];
    myb[16] = mreg;
    myb[17] = lreg;
  }
  __syncthreads();
  if (wave < 2) {
    const float* pb = cb + (size_t)wave * 1280 + lane * 20;
    f32x4 oB[4];
#pragma unroll
    for (int dd = 0; dd < 4; dd++) oB[dd] = *(const f32x4*)(pb + dd * 4);
    const float mB = pb[16], lB = pb[17];
    const float mst = fmaxf(mreg, mB);
    const float scA = __builtin_amdgcn_exp2f(mreg - mst);
    const float scB = __builtin_amdgcn_exp2f(mB - mst);
    lreg = lreg * scA + lB * scB;
#pragma unroll
    for (int dd = 0; dd < 4; dd++)
#pragma unroll
      for (int r = 0; r < 4; r++) oacc[dd][r] = oacc[dd][r] * scA + oB[dd][r] * scB;
    // reduce l across the 4 row-group lanes, write O
    lreg += __shfl_xor(lreg, 16);
    lreg += __shfl_xor(lreg, 32);
    const float inv = 1.f / lreg;
#pragma unroll
    for (int dd = 0; dd < 4; dd++) {
      uint2 u;
      u.x = pack2bf(oacc[dd][0] * inv, oacc[dd][1] * inv);
      u.y = pack2bf(oacc[dd][2] * inv, oacc[dd][3] * inv);
      *(uint2*)&attb[(size_t)(b * SQ + q) * DM + h * HDIM + dd * 16 + g * 4] = u;
    }
  }
}

// ---------------- host-side launch ----------------
extern "C" void kernel_launch(void* const* d_in, const int* in_sizes, int n_in,
                              void* d_out, int out_size, void* d_ws, size_t ws_size,
                              hipStream_t stream) {
  const float* x     = (const float*)d_in[0];
  const float* boxes = (const float*)d_in[1];
  const float* Wq    = (const float*)d_in[2];
  const float* bq    = (const float*)d_in[3];
  const float* Wk    = (const float*)d_in[4];
  const float* bk    = (const float*)d_in[5];
  const float* Wv    = (const float*)d_in[6];
  const float* bv    = (const float*)d_in[7];
  const float* Wo    = (const float*)d_in[8];
  const float* bo    = (const float*)d_in[9];
  const float* sb    = (const float*)d_in[10];

  char* ws = (char*)d_ws;
  unsigned short* xb   = (unsigned short*)(ws);             // 6291456 B
  unsigned short* wcat = (unsigned short*)(ws + 6291456);   // 3538944 B
  unsigned short* wob  = (unsigned short*)(ws + 9830400);   // 1179648 B
  unsigned short* qb   = (unsigned short*)(ws + 11010048);  // 6291456 B
  unsigned short* kb   = (unsigned short*)(ws + 17301504);  // 6291456 B
  unsigned short* vtb  = (unsigned short*)(ws + 23592960);  // 6291456 B
  unsigned short* attb = (unsigned short*)(ws + 29884416);  // 6291456 B
  float2* centers      = (float2*)(ws + 36175872);          // 32768 B  (total ~36.2 MB)
  float* out = (float*)d_out;

  prep_kernel<<<14608, 256, 0, stream>>>(x, Wq, Wk, Wv, Wo, boxes, xb, wcat, wob, centers);
  gemm_bt<0><<<32 * 18, 256, 0, stream>>>(xb, wcat, DM, 18, bq, bk, bv, qb, kb, vtb, nullptr);
  attn_kernel<<<1536, 256, 0, stream>>>(qb, kb, vtb, centers, sb, attb);
  gemm_bt<1><<<32 * 6, 256, 0, stream>>>(attb, wob, DM, 6, bo, nullptr, nullptr,
                                         nullptr, nullptr, nullptr, out);
}

// Round 9
// 96.954 us; speedup vs baseline: 1.9581x; 1.9581x over previous
//
#include <hip/hip_runtime.h>
#include <stdint.h>

#define NHEADS 12
#define HDIM   64
#define NB     4
#define SQ     1024
#define DM     768
#define NROWS  (NB*SQ)      // 4096
#define NWE    (DM*DM)      // 589824
#define NXE    (NROWS*DM)   // 3145728

typedef __attribute__((ext_vector_type(8))) short short8;
typedef __attribute__((ext_vector_type(4))) float f32x4;

__device__ __forceinline__ unsigned short f2bf(float f) {
  union { float f; unsigned u; } v; v.f = f;
  return (unsigned short)((v.u + 0x7fffu + ((v.u >> 16) & 1u)) >> 16);
}

// pack two fp32 -> two bf16 in a dword (lo = first arg), pure verified ALU
__device__ __forceinline__ unsigned pack2bf(float lo, float hi) {
  return (unsigned)f2bf(lo) | ((unsigned)f2bf(hi) << 16);
}

__device__ __forceinline__ void gload16(const void* g, void* l) {
  __builtin_amdgcn_global_load_lds((__attribute__((address_space(1))) void*)(void*)g,
                                   (__attribute__((address_space(3))) void*)l, 16, 0, 0);
}

// ---------------- prep: fp32 -> bf16 conversions + box centers ----------------
__global__ __launch_bounds__(256) void prep_kernel(
    const float* __restrict__ x, const float* __restrict__ Wq, const float* __restrict__ Wk,
    const float* __restrict__ Wv, const float* __restrict__ Wo, const float* __restrict__ boxes,
    unsigned short* __restrict__ xb, unsigned short* __restrict__ wcat,
    unsigned short* __restrict__ wob, float2* __restrict__ centers) {
  int i = blockIdx.x * 256 + threadIdx.x;
  if (i < NXE) { xb[i] = f2bf(x[i]); return; }
  i -= NXE;
  if (i < NWE) {
    wcat[i]           = f2bf(Wq[i]);
    wcat[NWE + i]     = f2bf(Wk[i]);
    wcat[2 * NWE + i] = f2bf(Wv[i]);
    wob[i]            = f2bf(Wo[i]);
    return;
  }
  i -= NWE;
  if (i < NROWS) {
    float4 bx = ((const float4*)boxes)[i];
    centers[i] = make_float2((bx.x + bx.z) * 0.5f, (bx.y + bx.w) * 0.5f);
  }
}

// ---------------- NT GEMM: C[M,N] = A[M,K] * B[N,K]^T  (bf16 in, fp32 acc) ----
// 128x128 tile, 4 waves (2x2 of 64x64), 16x16x32 bf16 MFMA, global_load_lds.
// EPI=0: QKV epilogue (Q scaled by 0.125*log2e for exp2-domain softmax)
// EPI=1: fp32 out = acc + b0[n]
template <int EPI>
__global__ __launch_bounds__(256, 2) void gemm_bt(
    const unsigned short* __restrict__ A, const unsigned short* __restrict__ Bw,
    int K, int tiles_n,
    const float* __restrict__ b0, const float* __restrict__ b1, const float* __restrict__ b2,
    unsigned short* __restrict__ outQ, unsigned short* __restrict__ outK,
    unsigned short* __restrict__ outVt, float* __restrict__ outF) {
  __shared__ unsigned short lA[128 * 32];
  __shared__ unsigned short lB[128 * 32];
  const int tid = threadIdx.x, wave = tid >> 6, lane = tid & 63;
  const int tm = blockIdx.x / tiles_n, tn = blockIdx.x % tiles_n;
  const int wr = wave >> 1, wc = wave & 1;
  const int g = lane >> 4, c16 = lane & 15, kb8 = g * 8;

  f32x4 acc[4][4];
#pragma unroll
  for (int m = 0; m < 4; m++)
#pragma unroll
    for (int n = 0; n < 4; n++) acc[m][n] = (f32x4){0.f, 0.f, 0.f, 0.f};

  const unsigned short* Abase = A + (size_t)tm * 128 * K;
  const unsigned short* Bbase = Bw + (size_t)tn * 128 * K;
  const int lin0 = wave * 1024 + lane * 16;
  const int row0 = lin0 >> 6, cb0 = lin0 & 63;
  const int lin1 = lin0 + 4096;
  const int row1 = lin1 >> 6, cb1 = lin1 & 63;

  for (int kt = 0; kt < K; kt += 32) {
    __syncthreads();
    gload16((const char*)(Abase + (size_t)row0 * K + kt) + cb0, (char*)lA + wave * 1024);
    gload16((const char*)(Abase + (size_t)row1 * K + kt) + cb1, (char*)lA + wave * 1024 + 4096);
    gload16((const char*)(Bbase + (size_t)row0 * K + kt) + cb0, (char*)lB + wave * 1024);
    gload16((const char*)(Bbase + (size_t)row1 * K + kt) + cb1, (char*)lB + wave * 1024 + 4096);
    __syncthreads();
    short8 a[4], b[4];
#pragma unroll
    for (int m = 0; m < 4; m++) a[m] = *(const short8*)&lA[(wr * 64 + m * 16 + c16) * 32 + kb8];
#pragma unroll
    for (int n = 0; n < 4; n++) b[n] = *(const short8*)&lB[(wc * 64 + n * 16 + c16) * 32 + kb8];
#pragma unroll
    for (int m = 0; m < 4; m++)
#pragma unroll
      for (int n = 0; n < 4; n++)
        acc[m][n] = __builtin_amdgcn_mfma_f32_16x16x32_bf16(a[m], b[n], acc[m][n], 0, 0, 0);
  }

  // C/D layout (m89): col = lane&15, row = (lane>>4)*4 + r
#pragma unroll
  for (int m = 0; m < 4; m++) {
    const int gm0 = tm * 128 + wr * 64 + m * 16 + g * 4;
    const int bb = gm0 >> 10, ss0 = gm0 & 1023;
#pragma unroll
    for (int n = 0; n < 4; n++) {
      const int gn = tn * 128 + wc * 64 + n * 16 + c16;
      if (EPI == 0) {
        const int which = gn / DM, nn = gn - which * DM;
        const int h = nn >> 6, dh = nn & 63;
        const float bias = (which == 0 ? b0 : which == 1 ? b1 : b2)[nn];
        // fold 1/sqrt(Dh) * log2(e) into Q (exp2-domain softmax)
        const float scale = (which == 0) ? 0.1803368801f : 1.0f;
        if (which == 2) {
          ushort4 pk;
          pk.x = f2bf(acc[m][n][0] + bias);
          pk.y = f2bf(acc[m][n][1] + bias);
          pk.z = f2bf(acc[m][n][2] + bias);
          pk.w = f2bf(acc[m][n][3] + bias);
          *(ushort4*)&outVt[(((size_t)bb * NHEADS + h) * HDIM + dh) * SQ + ss0] = pk;
        } else {
          unsigned short* dst = (which == 0 ? outQ : outK) + ((size_t)bb * NHEADS + h) * SQ * HDIM;
#pragma unroll
          for (int r = 0; r < 4; r++)
            dst[(size_t)(ss0 + r) * HDIM + dh] = f2bf((acc[m][n][r] + bias) * scale);
        }
      } else {
        const float bias = b0[gn];
#pragma unroll
        for (int r = 0; r < 4; r++)
          outF[(size_t)(gm0 + r) * DM + gn] = acc[m][n][r] + bias;
      }
    }
  }
}

// ---------------- fused spatial attention v6c (synchronous LDS staging) ------
// Swapped-operand flash, lane owns one q-row. K/V staged per tile via
// global_load_lds using gemm_bt's PROVEN pattern: barrier -> stage -> barrier
// -> compute (no DMA across the loop back-edge, no DMA in flight at exit --
// bisects the v6/v6b race). Centers via plain per-thread LDS store.
// XOR-swizzle on DMA source + LDS read (rule #21).
// grid: 768 blocks = 48 bh * 16 qtiles (4 waves * 16 rows), XCD-swizzled.
#define KVB  128
#define PSTR 136  // P row stride in shorts (128 + 8 pad)
__global__ __launch_bounds__(256, 3) void attn_kernel(
    const unsigned short* __restrict__ Qb, const unsigned short* __restrict__ Kb,
    const unsigned short* __restrict__ Vt, const float2* __restrict__ centers,
    const float* __restrict__ sbias, unsigned short* __restrict__ attb) {
  __shared__ unsigned short lK[KVB * HDIM];     // 16 KB: [128 rows][128 B] swizzled
  __shared__ unsigned short lV[HDIM * KVB];     // 16 KB: [64 rows][256 B] swizzled
  __shared__ float2 lcent[KVB];                 // 1 KB: this tile's token centers
  __shared__ unsigned short plds[4][16 * PSTR]; // 17408 B  (total 51200 -> 3 blk/CU)
  const int tid = threadIdx.x, wave = tid >> 6, lane = tid & 63;
  const int g = lane >> 4, c16 = lane & 15, kb8 = g * 8;
  const int bid = blockIdx.x;
  const int xcd = bid & 7, li = bid >> 3;       // li in 0..95
  const int bh = xcd * 6 + (li >> 4);
  const int qt = li & 15;
  const int b = bh / NHEADS, h = bh - b * NHEADS;
  const float sb = sbias[h] * 1.44269504f;      // exp2-domain bias coefficient

  const unsigned short* Qh = Qb + (size_t)bh * SQ * HDIM;
  const char* Kc = (const char*)(Kb + (size_t)bh * SQ * HDIM);  // row = 128 B
  const char* Vc = (const char*)(Vt + (size_t)bh * HDIM * SQ);  // row = 2048 B
  const float2* cent_g = centers + b * SQ;

  // staging source lane terms (swizzle pre-applied to global source, rule #21)
  const int l8 = lane >> 3, l7 = lane & 7;      // K: 8 rows x 128 B per 1KB chunk
  const int kLane = l8 * 128 + ((l7 * 16) ^ (l8 << 4));
  const int v16 = lane >> 4, m16 = lane & 15;   // V: 4 rows x 256 B per 1KB chunk

  const int q = qt * 64 + wave * 16 + c16;      // this lane's q-row
  short8 qf[2];
  qf[0] = *(const short8*)&Qh[(size_t)q * HDIM + kb8];
  qf[1] = *(const short8*)&Qh[(size_t)q * HDIM + 32 + kb8];
  const float2 cq = cent_g[q];

  float mreg = -1e30f, lreg = 0.f;              // lreg: per-lane partial sum
  f32x4 oacc[4];
#pragma unroll
  for (int dd = 0; dd < 4; dd++) oacc[dd] = (f32x4){0.f, 0.f, 0.f, 0.f};

  const int swk = (c16 & 7) << 4;               // read-side swizzle key
#pragma unroll 1
  for (int tb = 0; tb < SQ; tb += KVB) {
    __syncthreads();  // WAR: previous tile's LDS reads complete
    // --- stage K/V tile (8 DMAs/wave) + centers (plain store), then drain ---
    {
      const char* kbase = Kc + (size_t)tb * 128;
#pragma unroll
      for (int j = 0; j < 4; j++) {
        const int i = wave * 4 + j;
        gload16(kbase + i * 1024 + kLane, (char*)lK + i * 1024);
      }
      const char* vbase = Vc + (size_t)tb * 2;
#pragma unroll
      for (int j = 0; j < 4; j++) {
        const int i = wave * 4 + j;
        const int row = i * 4 + v16;
        gload16(vbase + (size_t)row * 2048 + ((m16 * 16) ^ ((4 * (i & 1) + v16) << 4)),
                (char*)lV + i * 1024);
      }
      if (tid < KVB) lcent[tid] = cent_g[tb + tid];
    }
    __syncthreads();  // RAW: vmcnt(0) drained + lcent visible
    // --- 1. QK^T from lK (swizzled b128 reads) ---
    f32x4 sv[8];
#pragma unroll
    for (int cc = 0; cc < 8; cc++) {
      const int rb = (cc * 16 + c16) * 128;
      short8 k0 = *(const short8*)((const char*)lK + rb + ((g * 16) ^ swk));
      short8 k1 = *(const short8*)((const char*)lK + rb + ((64 + g * 16) ^ swk));
      f32x4 s = (f32x4){0.f, 0.f, 0.f, 0.f};
      s = __builtin_amdgcn_mfma_f32_16x16x32_bf16(k0, qf[0], s, 0, 0, 0);
      s = __builtin_amdgcn_mfma_f32_16x16x32_bf16(k1, qf[1], s, 0, 0, 0);
      sv[cc] = s;
    }
    // --- 2. spatial bias from lcent (broadcast reads, raw v_sqrt) ---
#pragma unroll
    for (int cc = 0; cc < 8; cc++) {
      const float4* cp = (const float4*)&lcent[cc * 16 + g * 4];
      float4 c01 = cp[0], c23 = cp[1];
      float dx, dy;
      dx = cq.x - c01.x; dy = cq.y - c01.y;
      sv[cc][0] -= __builtin_amdgcn_sqrtf(dx * dx + dy * dy) * sb;
      dx = cq.x - c01.z; dy = cq.y - c01.w;
      sv[cc][1] -= __builtin_amdgcn_sqrtf(dx * dx + dy * dy) * sb;
      dx = cq.x - c23.x; dy = cq.y - c23.y;
      sv[cc][2] -= __builtin_amdgcn_sqrtf(dx * dx + dy * dy) * sb;
      dx = cq.x - c23.z; dy = cq.y - c23.w;
      sv[cc][3] -= __builtin_amdgcn_sqrtf(dx * dx + dy * dy) * sb;
    }
    // --- 3. defer-max online softmax (no shfl in common path) ---
    float lm = -1e30f;
#pragma unroll
    for (int cc = 0; cc < 8; cc++) {
      float a0 = fmaxf(sv[cc][0], sv[cc][1]), a1 = fmaxf(sv[cc][2], sv[cc][3]);
      lm = fmaxf(lm, fmaxf(a0, a1));
    }
    if (!__all(lm <= mreg + 8.0f)) {
      float vmax = fmaxf(lm, __shfl_xor(lm, 16));
      vmax = fmaxf(vmax, __shfl_xor(vmax, 32));
      const float mn = fmaxf(mreg, vmax);
      const float sc = __builtin_amdgcn_exp2f(mreg - mn);
      lreg *= sc;
#pragma unroll
      for (int dd = 0; dd < 4; dd++)
#pragma unroll
        for (int r = 0; r < 4; r++) oacc[dd][r] *= sc;
      mreg = mn;
    }
    float ps = 0.f;
#pragma unroll
    for (int cc = 0; cc < 8; cc++)
#pragma unroll
      for (int r = 0; r < 4; r++) {
        sv[cc][r] = __builtin_amdgcn_exp2f(sv[cc][r] - mreg);
        ps += sv[cc][r];
      }
    lreg += ps;
    // --- 4. P -> per-wave LDS [q-row][token] ---
#pragma unroll
    for (int cc = 0; cc < 8; cc++) {
      uint2 u;
      u.x = pack2bf(sv[cc][0], sv[cc][1]);
      u.y = pack2bf(sv[cc][2], sv[cc][3]);
      *(uint2*)&plds[wave][c16 * PSTR + cc * 16 + g * 4] = u;
    }
    // --- 5. PV from lV (swizzled) + plds ---
#pragma unroll
    for (int kc = 0; kc < 4; kc++) {
      short8 pf = *(const short8*)&plds[wave][c16 * PSTR + kc * 32 + kb8];
#pragma unroll
      for (int dd = 0; dd < 4; dd++) {
        short8 vf = *(const short8*)((const char*)lV + (dd * 16 + c16) * 256 +
                                     ((kc * 64 + g * 16) ^ swk));
        oacc[dd] = __builtin_amdgcn_mfma_f32_16x16x32_bf16(vf, pf, oacc[dd], 0, 0, 0);
      }
    }
  }
  // --- epilogue: reduce l across the 4 row-group lanes, write O ---
  lreg += __shfl_xor(lreg, 16);
  lreg += __shfl_xor(lreg, 32);
  const float inv = 1.f / lreg;
#pragma unroll
  for (int dd = 0; dd < 4; dd++) {
    uint2 u;
    u.x = pack2bf(oacc[dd][0] * inv, oacc[dd][1] * inv);
    u.y = pack2bf(oacc[dd][2] * inv, oacc[dd][3] * inv);
    *(uint2*)&attb[(size_t)(b * SQ + q) * DM + h * HDIM + dd * 16 + g * 4] = u;
  }
}

// ---------------- host-side launch ----------------
extern "C" void kernel_launch(void* const* d_in, const int* in_sizes, int n_in,
                              void* d_out, int out_size, void* d_ws, size_t ws_size,
                              hipStream_t stream) {
  const float* x     = (const float*)d_in[0];
  const float* boxes = (const float*)d_in[1];
  const float* Wq    = (const float*)d_in[2];
  const float* bq    = (const float*)d_in[3];
  const float* Wk    = (const float*)d_in[4];
  const float* bk    = (const float*)d_in[5];
  const float* Wv    = (const float*)d_in[6];
  const float* bv    = (const float*)d_in[7];
  const float* Wo    = (const float*)d_in[8];
  const float* bo    = (const float*)d_in[9];
  const float* sb    = (const float*)d_in[10];

  char* ws = (char*)d_ws;
  unsigned short* xb   = (unsigned short*)(ws);             // 6291456 B
  unsigned short* wcat = (unsigned short*)(ws + 6291456);   // 3538944 B
  unsigned short* wob  = (unsigned short*)(ws + 9830400);   // 1179648 B
  unsigned short* qb   = (unsigned short*)(ws + 11010048);  // 6291456 B
  unsigned short* kb   = (unsigned short*)(ws + 17301504);  // 6291456 B
  unsigned short* vtb  = (unsigned short*)(ws + 23592960);  // 6291456 B
  unsigned short* attb = (unsigned short*)(ws + 29884416);  // 6291456 B
  float2* centers      = (float2*)(ws + 36175872);          // 32768 B  (total ~36.2 MB)
  float* out = (float*)d_out;

  prep_kernel<<<14608, 256, 0, stream>>>(x, Wq, Wk, Wv, Wo, boxes, xb, wcat, wob, centers);
  gemm_bt<0><<<32 * 18, 256, 0, stream>>>(xb, wcat, DM, 18, bq, bk, bv, qb, kb, vtb, nullptr);
  attn_kernel<<<768, 256, 0, stream>>>(qb, kb, vtb, centers, sb, attb);
  gemm_bt<1><<<32 * 6, 256, 0, stream>>>(attb, wob, DM, 6, bo, nullptr, nullptr,
                                         nullptr, nullptr, nullptr, out);
}

// Round 10
// 93.757 us; speedup vs baseline: 2.0249x; 1.0341x over previous
//
#include <hip/hip_runtime.h>
#include <stdint.h>

#define NHEADS 12
#define HDIM   64
#define NB     4
#define SQ     1024
#define DM     768
#define NROWS  (NB*SQ)      // 4096
#define NWE    (DM*DM)      // 589824
#define NXE    (NROWS*DM)   // 3145728

typedef __attribute__((ext_vector_type(8))) short short8;
typedef __attribute__((ext_vector_type(4))) float f32x4;

__device__ __forceinline__ unsigned short f2bf(float f) {
  union { float f; unsigned u; } v; v.f = f;
  return (unsigned short)((v.u + 0x7fffu + ((v.u >> 16) & 1u)) >> 16);
}

// pack two fp32 -> two bf16 in a dword (lo = first arg), pure verified ALU
__device__ __forceinline__ unsigned pack2bf(float lo, float hi) {
  return (unsigned)f2bf(lo) | ((unsigned)f2bf(hi) << 16);
}

__device__ __forceinline__ void gload16(const void* g, void* l) {
  __builtin_amdgcn_global_load_lds((__attribute__((address_space(1))) void*)(void*)g,
                                   (__attribute__((address_space(3))) void*)l, 16, 0, 0);
}

// explicit DMA drain: the compiler does NOT emit vmcnt(0) at barriers whose
// global_load_lds were issued before a loop back-edge (v6 race, round 7/8).
__device__ __forceinline__ void drain_dma() {
  asm volatile("s_waitcnt vmcnt(0)" ::: "memory");
  __builtin_amdgcn_sched_barrier(0);
}

// ---------------- prep: fp32 -> bf16 conversions + box centers ----------------
__global__ __launch_bounds__(256) void prep_kernel(
    const float* __restrict__ x, const float* __restrict__ Wq, const float* __restrict__ Wk,
    const float* __restrict__ Wv, const float* __restrict__ Wo, const float* __restrict__ boxes,
    unsigned short* __restrict__ xb, unsigned short* __restrict__ wcat,
    unsigned short* __restrict__ wob, float2* __restrict__ centers) {
  int i = blockIdx.x * 256 + threadIdx.x;
  if (i < NXE) { xb[i] = f2bf(x[i]); return; }
  i -= NXE;
  if (i < NWE) {
    wcat[i]           = f2bf(Wq[i]);
    wcat[NWE + i]     = f2bf(Wk[i]);
    wcat[2 * NWE + i] = f2bf(Wv[i]);
    wob[i]            = f2bf(Wo[i]);
    return;
  }
  i -= NWE;
  if (i < NROWS) {
    float4 bx = ((const float4*)boxes)[i];
    centers[i] = make_float2((bx.x + bx.z) * 0.5f, (bx.y + bx.w) * 0.5f);
  }
}

// ---------------- NT GEMM: C[M,N] = A[M,K] * B[N,K]^T  (bf16 in, fp32 acc) ----
// BMxBN tile, 4 waves (2x2), 16x16x32 bf16 MFMA, double-buffered
// global_load_lds staging with explicit vmcnt drain (1 barrier per K-step).
// EPI=0: QKV epilogue (Q scaled by 0.125*log2e for exp2-domain softmax)
// EPI=1: fp32 out = acc + b0[n]
template <int EPI, int BM, int BN>
__global__ __launch_bounds__(256, 2) void gemm_bt(
    const unsigned short* __restrict__ A, const unsigned short* __restrict__ Bw,
    int K, int tiles_n,
    const float* __restrict__ b0, const float* __restrict__ b1, const float* __restrict__ b2,
    unsigned short* __restrict__ outQ, unsigned short* __restrict__ outK,
    unsigned short* __restrict__ outVt, float* __restrict__ outF) {
  constexpr int MF = BM / 32, NF = BN / 32;  // frags per wave (wave owns BM/2 x BN/2)
  __shared__ unsigned short lA[2][BM * 32];
  __shared__ unsigned short lB[2][BN * 32];
  const int tid = threadIdx.x, wave = tid >> 6, lane = tid & 63;
  const int tm = blockIdx.x / tiles_n, tn = blockIdx.x % tiles_n;
  const int wr = wave >> 1, wc = wave & 1;
  const int g = lane >> 4, c16 = lane & 15, kb8 = g * 8;

  f32x4 acc[MF][NF];
#pragma unroll
  for (int m = 0; m < MF; m++)
#pragma unroll
    for (int n = 0; n < NF; n++) acc[m][n] = (f32x4){0.f, 0.f, 0.f, 0.f};

  const unsigned short* Abase = A + (size_t)tm * BM * K;
  const unsigned short* Bbase = Bw + (size_t)tn * BN * K;
  const int srow = lane >> 2, scb = (lane & 3) << 4;  // 16 rows/chunk, 64B rows

  auto stage = [&](int kt, int s) {
#pragma unroll
    for (int c = wave; c < BM / 16; c += 4)
      gload16((const char*)(Abase + (size_t)(c * 16 + srow) * K + kt) + scb,
              (char*)lA[s] + c * 1024);
#pragma unroll
    for (int c = wave; c < BN / 16; c += 4)
      gload16((const char*)(Bbase + (size_t)(c * 16 + srow) * K + kt) + scb,
              (char*)lB[s] + c * 1024);
  };

  stage(0, 0);
  const int nk = K >> 5;
#pragma unroll 1
  for (int i = 0; i < nk; i++) {
    drain_dma();      // buf[i&1] landed (all waves after barrier)
    __syncthreads();
    if (i + 1 < nk) stage((i + 1) * 32, (i + 1) & 1);  // overlaps with compute
    const unsigned short* sA = lA[i & 1];
    const unsigned short* sB = lB[i & 1];
    short8 a[MF], b[NF];
#pragma unroll
    for (int m = 0; m < MF; m++)
      a[m] = *(const short8*)&sA[(wr * (BM / 2) + m * 16 + c16) * 32 + kb8];
#pragma unroll
    for (int n = 0; n < NF; n++)
      b[n] = *(const short8*)&sB[(wc * (BN / 2) + n * 16 + c16) * 32 + kb8];
#pragma unroll
    for (int m = 0; m < MF; m++)
#pragma unroll
      for (int n = 0; n < NF; n++)
        acc[m][n] = __builtin_amdgcn_mfma_f32_16x16x32_bf16(a[m], b[n], acc[m][n], 0, 0, 0);
  }

  // C/D layout (m89): col = lane&15, row = (lane>>4)*4 + r
#pragma unroll
  for (int m = 0; m < MF; m++) {
    const int gm0 = tm * BM + wr * (BM / 2) + m * 16 + g * 4;
    const int bb = gm0 >> 10, ss0 = gm0 & 1023;
#pragma unroll
    for (int n = 0; n < NF; n++) {
      const int gn = tn * BN + wc * (BN / 2) + n * 16 + c16;
      if (EPI == 0) {
        const int which = gn / DM, nn = gn - which * DM;
        const int h = nn >> 6, dh = nn & 63;
        const float bias = (which == 0 ? b0 : which == 1 ? b1 : b2)[nn];
        // fold 1/sqrt(Dh) * log2(e) into Q (exp2-domain softmax)
        const float scale = (which == 0) ? 0.1803368801f : 1.0f;
        if (which == 2) {
          ushort4 pk;
          pk.x = f2bf(acc[m][n][0] + bias);
          pk.y = f2bf(acc[m][n][1] + bias);
          pk.z = f2bf(acc[m][n][2] + bias);
          pk.w = f2bf(acc[m][n][3] + bias);
          *(ushort4*)&outVt[(((size_t)bb * NHEADS + h) * HDIM + dh) * SQ + ss0] = pk;
        } else {
          unsigned short* dst = (which == 0 ? outQ : outK) + ((size_t)bb * NHEADS + h) * SQ * HDIM;
#pragma unroll
          for (int r = 0; r < 4; r++)
            dst[(size_t)(ss0 + r) * HDIM + dh] = f2bf((acc[m][n][r] + bias) * scale);
        }
      } else {
        const float bias = b0[gn];
#pragma unroll
        for (int r = 0; r < 4; r++)
          outF[(size_t)(gm0 + r) * DM + gn] = acc[m][n][r] + bias;
      }
    }
  }
}

// ---------------- fused spatial attention v7 (double-buffered LDS staging) ---
// Swapped-operand flash, lane owns one q-row. KVB=64, K/V/cent double-buffered:
// per tile, ONE barrier + explicit vmcnt drain; stage(t+1) overlaps compute(t).
// XOR-swizzle on DMA source + LDS read (rule #21), proven in v6c.
// grid: 768 blocks = 48 bh * 16 qtiles (4 waves * 16 rows), XCD-swizzled.
#define KVB  64
#define PSTR 72   // P row stride in shorts (64 + 8 pad)
__global__ __launch_bounds__(256, 3) void attn_kernel(
    const unsigned short* __restrict__ Qb, const unsigned short* __restrict__ Kb,
    const unsigned short* __restrict__ Vt, const float2* __restrict__ centers,
    const float* __restrict__ sbias, unsigned short* __restrict__ attb) {
  __shared__ unsigned short lK[2][KVB * HDIM];  // 2 x 8 KB, [64 rows][128 B] swizzled
  __shared__ unsigned short lV[2][HDIM * KVB];  // 2 x 8 KB, [64 rows][128 B] swizzled
  __shared__ float2 lcent[2][KVB];              // 2 x 512 B
  __shared__ unsigned short plds[4][16 * PSTR]; // 9216 B   (total 43008 -> 3 blk/CU)
  const int tid = threadIdx.x, wave = tid >> 6, lane = tid & 63;
  const int g = lane >> 4, c16 = lane & 15, kb8 = g * 8;
  const int bid = blockIdx.x;
  const int xcd = bid & 7, li = bid >> 3;       // li in 0..95
  const int bh = xcd * 6 + (li >> 4);
  const int qt = li & 15;
  const int b = bh / NHEADS, h = bh - b * NHEADS;
  const float sb = sbias[h] * 1.44269504f;      // exp2-domain bias coefficient

  const unsigned short* Qh = Qb + (size_t)bh * SQ * HDIM;
  const char* Kc = (const char*)(Kb + (size_t)bh * SQ * HDIM);  // K row = 128 B
  const char* Vc = (const char*)(Vt + (size_t)bh * HDIM * SQ);  // V row = 2048 B
  const float2* cent_g = centers + b * SQ;

  // staging lane terms (swizzle pre-applied to global source, rule #21)
  const int l8 = lane >> 3, l7 = lane & 7;      // 8 rows x 128 B per 1KB chunk
  const int swizL = (l7 * 16) ^ (l8 << 4);

  // stage one 64-token tile into buffer s: K 8 chunks, V 8 chunks (2/wave each)
  auto stage = [&](int tbn, int s) {
    const char* kbase = Kc + (size_t)tbn * 128;
#pragma unroll
    for (int j = 0; j < 2; j++) {
      const int i = wave * 2 + j;
      gload16(kbase + i * 1024 + l8 * 128 + swizL, (char*)lK[s] + i * 1024);
    }
    const char* vbase = Vc + (size_t)tbn * 2;
#pragma unroll
    for (int j = 0; j < 2; j++) {
      const int i = wave * 2 + j;
      gload16(vbase + (size_t)(i * 8 + l8) * 2048 + swizL, (char*)lV[s] + i * 1024);
    }
    if (tid < KVB) lcent[s][tid] = cent_g[tbn + tid];
  };

  const int q = qt * 64 + wave * 16 + c16;      // this lane's q-row
  short8 qf[2];
  qf[0] = *(const short8*)&Qh[(size_t)q * HDIM + kb8];
  qf[1] = *(const short8*)&Qh[(size_t)q * HDIM + 32 + kb8];
  const float2 cq = cent_g[q];

  float mreg = -1e30f, lreg = 0.f;              // lreg: per-lane partial sum
  f32x4 oacc[4];
#pragma unroll
  for (int dd = 0; dd < 4; dd++) oacc[dd] = (f32x4){0.f, 0.f, 0.f, 0.f};

  stage(0, 0);

  const int swk = (c16 & 7) << 4;               // read-side swizzle key
#pragma unroll 1
  for (int t = 0; t < SQ / KVB; t++) {
    const int cur = t & 1;
    drain_dma();      // buf[cur] landed (all waves after barrier)
    __syncthreads();
    if (t + 1 < SQ / KVB) stage((t + 1) * KVB, cur ^ 1);  // overlaps with compute
    // --- 1. QK^T from lK (swizzled b128 reads) ---
    f32x4 sv[4];
#pragma unroll
    for (int cc = 0; cc < 4; cc++) {
      const int rb = (cc * 16 + c16) * 128;
      short8 k0 = *(const short8*)((const char*)lK[cur] + rb + ((g * 16) ^ swk));
      short8 k1 = *(const short8*)((const char*)lK[cur] + rb + ((64 + g * 16) ^ swk));
      f32x4 s = (f32x4){0.f, 0.f, 0.f, 0.f};
      s = __builtin_amdgcn_mfma_f32_16x16x32_bf16(k0, qf[0], s, 0, 0, 0);
      s = __builtin_amdgcn_mfma_f32_16x16x32_bf16(k1, qf[1], s, 0, 0, 0);
      sv[cc] = s;
    }
    // --- 2. spatial bias from lcent (broadcast reads, raw v_sqrt) ---
#pragma unroll
    for (int cc = 0; cc < 4; cc++) {
      const float4* cp = (const float4*)&lcent[cur][cc * 16 + g * 4];
      float4 c01 = cp[0], c23 = cp[1];
      float dx, dy;
      dx = cq.x - c01.x; dy = cq.y - c01.y;
      sv[cc][0] -= __builtin_amdgcn_sqrtf(dx * dx + dy * dy) * sb;
      dx = cq.x - c01.z; dy = cq.y - c01.w;
      sv[cc][1] -= __builtin_amdgcn_sqrtf(dx * dx + dy * dy) * sb;
      dx = cq.x - c23.x; dy = cq.y - c23.y;
      sv[cc][2] -= __builtin_amdgcn_sqrtf(dx * dx + dy * dy) * sb;
      dx = cq.x - c23.z; dy = cq.y - c23.w;
      sv[cc][3] -= __builtin_amdgcn_sqrtf(dx * dx + dy * dy) * sb;
    }
    // --- 3. defer-max online softmax (no shfl in common path) ---
    float lm = -1e30f;
#pragma unroll
    for (int cc = 0; cc < 4; cc++) {
      float a0 = fmaxf(sv[cc][0], sv[cc][1]), a1 = fmaxf(sv[cc][2], sv[cc][3]);
      lm = fmaxf(lm, fmaxf(a0, a1));
    }
    if (!__all(lm <= mreg + 8.0f)) {
      float vmax = fmaxf(lm, __shfl_xor(lm, 16));
      vmax = fmaxf(vmax, __shfl_xor(vmax, 32));
      const float mn = fmaxf(mreg, vmax);
      const float sc = __builtin_amdgcn_exp2f(mreg - mn);
      lreg *= sc;
#pragma unroll
      for (int dd = 0; dd < 4; dd++)
#pragma unroll
        for (int r = 0; r < 4; r++) oacc[dd][r] *= sc;
      mreg = mn;
    }
    float ps = 0.f;
#pragma unroll
    for (int cc = 0; cc < 4; cc++)
#pragma unroll
      for (int r = 0; r < 4; r++) {
        sv[cc][r] = __builtin_amdgcn_exp2f(sv[cc][r] - mreg);
        ps += sv[cc][r];
      }
    lreg += ps;
    // --- 4. P -> per-wave LDS [q-row][token] ---
#pragma unroll
    for (int cc = 0; cc < 4; cc++) {
      uint2 u;
      u.x = pack2bf(sv[cc][0], sv[cc][1]);
      u.y = pack2bf(sv[cc][2], sv[cc][3]);
      *(uint2*)&plds[wave][c16 * PSTR + cc * 16 + g * 4] = u;
    }
    // --- 5. PV from lV (swizzled) + plds ---
#pragma unroll
    for (int kc = 0; kc < 2; kc++) {
      short8 pf = *(const short8*)&plds[wave][c16 * PSTR + kc * 32 + kb8];
#pragma unroll
      for (int dd = 0; dd < 4; dd++) {
        short8 vf = *(const short8*)((const char*)lV[cur] + (dd * 16 + c16) * 128 +
                                     ((kc * 64 + g * 16) ^ swk));
        oacc[dd] = __builtin_amdgcn_mfma_f32_16x16x32_bf16(vf, pf, oacc[dd], 0, 0, 0);
      }
    }
  }
  // --- epilogue: reduce l across the 4 row-group lanes, write O ---
  lreg += __shfl_xor(lreg, 16);
  lreg += __shfl_xor(lreg, 32);
  const float inv = 1.f / lreg;
#pragma unroll
  for (int dd = 0; dd < 4; dd++) {
    uint2 u;
    u.x = pack2bf(oacc[dd][0] * inv, oacc[dd][1] * inv);
    u.y = pack2bf(oacc[dd][2] * inv, oacc[dd][3] * inv);
    *(uint2*)&attb[(size_t)(b * SQ + q) * DM + h * HDIM + dd * 16 + g * 4] = u;
  }
}

// ---------------- host-side launch ----------------
extern "C" void kernel_launch(void* const* d_in, const int* in_sizes, int n_in,
                              void* d_out, int out_size, void* d_ws, size_t ws_size,
                              hipStream_t stream) {
  const float* x     = (const float*)d_in[0];
  const float* boxes = (const float*)d_in[1];
  const float* Wq    = (const float*)d_in[2];
  const float* bq    = (const float*)d_in[3];
  const float* Wk    = (const float*)d_in[4];
  const float* bk    = (const float*)d_in[5];
  const float* Wv    = (const float*)d_in[6];
  const float* bv    = (const float*)d_in[7];
  const float* Wo    = (const float*)d_in[8];
  const float* bo    = (const float*)d_in[9];
  const float* sb    = (const float*)d_in[10];

  char* ws = (char*)d_ws;
  unsigned short* xb   = (unsigned short*)(ws);             // 6291456 B
  unsigned short* wcat = (unsigned short*)(ws + 6291456);   // 3538944 B
  unsigned short* wob  = (unsigned short*)(ws + 9830400);   // 1179648 B
  unsigned short* qb   = (unsigned short*)(ws + 11010048);  // 6291456 B
  unsigned short* kb   = (unsigned short*)(ws + 17301504);  // 6291456 B
  unsigned short* vtb  = (unsigned short*)(ws + 23592960);  // 6291456 B
  unsigned short* attb = (unsigned short*)(ws + 29884416);  // 6291456 B
  float2* centers      = (float2*)(ws + 36175872);          // 32768 B  (total ~36.2 MB)
  float* out = (float*)d_out;

  prep_kernel<<<14608, 256, 0, stream>>>(x, Wq, Wk, Wv, Wo, boxes, xb, wcat, wob, centers);
  gemm_bt<0, 128, 128><<<32 * 18, 256, 0, stream>>>(xb, wcat, DM, 18, bq, bk, bv,
                                                    qb, kb, vtb, nullptr);
  attn_kernel<<<768, 256, 0, stream>>>(qb, kb, vtb, centers, sb, attb);
  gemm_bt<1, 64, 64><<<64 * 12, 256, 0, stream>>>(attb, wob, DM, 12, bo, nullptr, nullptr,
                                                  nullptr, nullptr, nullptr, out);
}